// Round 8
// baseline (281.364 us; speedup 1.0000x reference)
//
#include <hip/hip_runtime.h>
#include <math.h>

#define NEG_SLOPE 0.2f
#define CAP 256     // max degree on the agg fast path
#define BSH 9       // node-bucket shift: 512 nodes/bucket
#define BSZ 512
#define CHUNK 2048  // edges per k_scatter block
#define PADS 16     // counter padding (ints) -> one counter per 64B line

typedef __attribute__((ext_vector_type(8))) short short8;   // 8 bf16 (4 VGPRs)
typedef __attribute__((ext_vector_type(4))) float f32x4;    // MFMA C/D

__device__ __forceinline__ float hred_sum(float v) {   // 32-wide (half-wave) reduce
#pragma unroll
    for (int o = 16; o >= 1; o >>= 1) v += __shfl_xor(v, o, 64);
    return v;
}
// fp32 -> bf16 (RNE), and bf16(lo/hi of uint) -> fp32
__device__ __forceinline__ unsigned int f2bf(float f) {
    unsigned int u = __float_as_uint(f);
    return (u + 0x7fffu + ((u >> 16) & 1u)) >> 16;
}
__device__ __forceinline__ float bflo(unsigned int u) { return __uint_as_float(u << 16); }
__device__ __forceinline__ float bfhi(unsigned int u) { return __uint_as_float(u & 0xffff0000u); }

// ---------------- CSR build: bucketed counting sort ----------------

__global__ __launch_bounds__(256) void k_zero(int* p, int n) {
    int i = blockIdx.x * 256 + threadIdx.x;
    if (i < n) p[i] = 0;
}

__global__ __launch_bounds__(256) void k_hist(const int* __restrict__ dst, int* __restrict__ bcount, int E) {
    __shared__ int lh[256];
    lh[threadIdx.x] = 0;
    __syncthreads();
    int stride = gridDim.x * 256;
    for (int i = blockIdx.x * 256 + threadIdx.x; i < E; i += stride)
        atomicAdd(&lh[dst[i] >> BSH], 1);
    __syncthreads();
    int c = lh[threadIdx.x];
    if (c) atomicAdd(&bcount[threadIdx.x * PADS], c);
}

__global__ __launch_bounds__(256) void k_bscan(const int* __restrict__ bcount,
                                               int* __restrict__ eoff, int* __restrict__ boff,
                                               int* __restrict__ bcursor, int* __restrict__ rowptr,
                                               int nbuck, int N, int E) {
    __shared__ int s1[256], s2[256];
    int t = threadIdx.x;
    int bc = (t < nbuck) ? bcount[t * PADS] : 0;
    int cn = 0;
    if (t < nbuck) { cn = N - (t << BSH); if (cn > BSZ) cn = BSZ; if (cn < 0) cn = 0; }
    int tot = bc + cn;
    s1[t] = bc; s2[t] = tot;
    __syncthreads();
#pragma unroll
    for (int off = 1; off < 256; off <<= 1) {
        int u1 = (t >= off) ? s1[t - off] : 0;
        int u2 = (t >= off) ? s2[t - off] : 0;
        __syncthreads();
        s1[t] += u1; s2[t] += u2;
        __syncthreads();
    }
    if (t < nbuck) {
        int e = s1[t] - bc, b = s2[t] - tot;
        eoff[t] = e; boff[t] = b; bcursor[t * PADS] = e;
    }
    if (t == 0) rowptr[N] = E + N;
}

__global__ __launch_bounds__(256) void k_scatter(const int* __restrict__ src, const int* __restrict__ dst,
                                                 int* __restrict__ bcursor, int* __restrict__ ebuf, int E) {
    __shared__ int lh[256], lb[256];
    int base = blockIdx.x * CHUNK;
    int end = base + CHUNK; if (end > E) end = E;
    lh[threadIdx.x] = 0;
    __syncthreads();
    for (int i = base + threadIdx.x; i < end; i += 256)
        atomicAdd(&lh[dst[i] >> BSH], 1);
    __syncthreads();
    int c = lh[threadIdx.x];
    lb[threadIdx.x] = c ? atomicAdd(&bcursor[threadIdx.x * PADS], c) : 0;
    lh[threadIdx.x] = 0;
    __syncthreads();
    for (int i = base + threadIdx.x; i < end; i += 256) {
        int d = dst[i], b = d >> BSH;
        int p = atomicAdd(&lh[b], 1);
        ebuf[lb[b] + p] = (src[i] << BSH) | (d & (BSZ - 1));
    }
}

__global__ __launch_bounds__(512) void k_build(const int* __restrict__ eoff, const int* __restrict__ boff,
                                               const int* __restrict__ bcount, const int* __restrict__ ebuf,
                                               int* __restrict__ rowptr, int* __restrict__ csr, int N) {
    __shared__ int sdeg[BSZ], sscan[BSZ];
    int b = blockIdx.x, t = threadIdx.x;
    int nlo = b << BSH;
    int cn = N - nlo; if (cn > BSZ) cn = BSZ;
    int e0 = eoff[b], ec = bcount[b * PADS], cb = boff[b];
    sdeg[t] = (t < cn) ? 1 : 0;
    __syncthreads();
    for (int i = t; i < ec; i += 512)
        atomicAdd(&sdeg[ebuf[e0 + i] & (BSZ - 1)], 1);
    __syncthreads();
    int v = sdeg[t];
    sscan[t] = v;
    __syncthreads();
#pragma unroll
    for (int off = 1; off < BSZ; off <<= 1) {
        int u = (t >= off) ? sscan[t - off] : 0;
        __syncthreads();
        sscan[t] += u;
        __syncthreads();
    }
    int excl = sscan[t] - v;
    if (t < cn) {
        rowptr[nlo + t] = cb + excl;
        csr[cb + excl] = nlo + t;
        sdeg[t] = excl + 1;
    }
    __syncthreads();
    for (int i = t; i < ec; i += 512) {
        int rec = ebuf[e0 + i];
        int p = atomicAdd(&sdeg[rec & (BSZ - 1)], 1);
        csr[cb + p] = rec >> BSH;
    }
}

// ---------------- GEMM via bf16 MFMA, split-precision A ----------------------
// H = X @ W (+bias). Block = 256 = 4 waves; each wave: 16 rows x OUTW cols.
// A = xh + xl (two bf16 terms, ~fp32 accuracy); W plain bf16 (error ~6e-4).
// W pre-packed in LDS as B-fragments (one barrier total). A-frags loaded
// directly from global (block's rows are L1-resident). MFMA 16x16x32:
//   A[m=lane&15][k=(lane>>4)*8+j], B[k][n=lane&15], C/D row=(lane>>4)*4+i.

template <int K, int OUTW, bool SS, bool HB>
__global__ __launch_bounds__(256) void k_gemm(const float* __restrict__ X,
                                              const float* __restrict__ W,
                                              const float* __restrict__ a_s,
                                              const float* __restrict__ a_d,
                                              const float* __restrict__ bias,
                                              void* __restrict__ Hout,
                                              float* __restrict__ ss,
                                              float* __restrict__ sd, int N) {
    constexpr int NKC = K / 32;               // k32 chunks
    constexpr int NC  = (OUTW + 15) / 16;     // 16-col tiles
    __shared__ __align__(16) short wfrag[NKC * NC * 64 * 8];
    __shared__ __align__(16) unsigned int hs[HB ? 4 : 1][16 * 32];  // per-wave epilogue

    const int tid  = threadIdx.x;
    const int lane = tid & 63;
    const int w    = tid >> 6;
    const int m    = lane & 15;     // A row / B col / C col
    const int q8   = lane >> 4;     // k-octet / C row-quad
    const int rowbase = blockIdx.x * 64 + w * 16;

    // stage W as pre-packed B-fragments (once)
    for (int f = tid; f < NKC * NC * 64; f += 256) {
        int flane = f & 63;
        int fc    = (f >> 6) % NC;
        int fkc   = (f >> 6) / NC;
        int col   = fc * 16 + (flane & 15);
        int k0    = fkc * 32 + (flane >> 4) * 8;
        short8 b;
#pragma unroll
        for (int j = 0; j < 8; ++j) {
            float v = (col < OUTW) ? W[(k0 + j) * OUTW + col] : 0.f;
            b[j] = (short)f2bf(v);
        }
        *(short8*)&wfrag[f * 8] = b;
    }
    __syncthreads();

    int grow = rowbase + m; if (grow >= N) grow = N - 1;
    const float* xrow = X + (size_t)grow * K + q8 * 8;

    f32x4 acc[NC];
#pragma unroll
    for (int c = 0; c < NC; ++c) acc[c] = (f32x4)0.f;

#pragma unroll
    for (int kc = 0; kc < NKC; ++kc) {
        float4 v0 = *(const float4*)(xrow + kc * 32);
        float4 v1 = *(const float4*)(xrow + kc * 32 + 4);
        float vv[8] = {v0.x, v0.y, v0.z, v0.w, v1.x, v1.y, v1.z, v1.w};
        short8 ah, al;
#pragma unroll
        for (int j = 0; j < 8; ++j) {
            unsigned int hb16 = f2bf(vv[j]);
            ah[j] = (short)hb16;
            al[j] = (short)f2bf(vv[j] - __uint_as_float(hb16 << 16));
        }
#pragma unroll
        for (int c = 0; c < NC; ++c) {
            short8 b = *(short8*)&wfrag[((kc * NC + c) * 64 + lane) * 8];
            acc[c] = __builtin_amdgcn_mfma_f32_16x16x32_bf16(ah, b, acc[c], 0, 0, 0);
            acc[c] = __builtin_amdgcn_mfma_f32_16x16x32_bf16(al, b, acc[c], 0, 0, 0);
        }
    }

    if (SS) {
        float asv[NC], adv[NC];
#pragma unroll
        for (int c = 0; c < NC; ++c) { asv[c] = a_s[c * 16 + m]; adv[c] = a_d[c * 16 + m]; }
#pragma unroll
        for (int i = 0; i < 4; ++i) {
            float s = 0.f, d = 0.f;
#pragma unroll
            for (int c = 0; c < NC; ++c) {
                s = fmaf(acc[c][i], asv[c], s);
                d = fmaf(acc[c][i], adv[c], d);
            }
#pragma unroll
            for (int o = 1; o <= 8; o <<= 1) {   // reduce the 16 col-lanes of this q8 group
                s += __shfl_xor(s, o, 64);
                d += __shfl_xor(d, o, 64);
            }
            int r = rowbase + q8 * 4 + i;
            if (m == 0 && r < N) { ss[r] = s; sd[r] = d; }
        }
    }

    if (HB) {
        // per-wave LDS transpose to bf16-packed rows (same-wave, no barrier needed)
        unsigned short* hsw = (unsigned short*)&hs[w][0];   // [16 rows][64 cols] bf16
#pragma unroll
        for (int c = 0; c < NC; ++c)
#pragma unroll
            for (int i = 0; i < 4; ++i)
                hsw[(q8 * 4 + i) * 64 + c * 16 + m] = (unsigned short)f2bf(acc[c][i]);
        unsigned int* hu = &hs[w][0];
        int row = lane >> 2, u0 = (lane & 3) * 8;
        uint4 va = *(uint4*)&hu[row * 32 + u0];
        uint4 vb = *(uint4*)&hu[row * 32 + u0 + 4];
        int r = rowbase + row;
        if (r < N) {
            unsigned int* hbp = (unsigned int*)Hout;
            *(uint4*)&hbp[(size_t)r * 32 + u0]     = va;
            *(uint4*)&hbp[(size_t)r * 32 + u0 + 4] = vb;
        }
    } else {
        float bv[NC];
#pragma unroll
        for (int c = 0; c < NC; ++c) {
            int col = c * 16 + m;
            bv[c] = (col < OUTW) ? bias[col] : 0.f;
        }
        float* O = (float*)Hout;
#pragma unroll
        for (int i = 0; i < 4; ++i) {
            int r = rowbase + q8 * 4 + i;
            if (r < N) {
#pragma unroll
                for (int c = 0; c < NC; ++c) {
                    int col = c * 16 + m;
                    if (col < OUTW) O[(size_t)r * OUTW + col] = acc[c][i] + bv[c];
                }
            }
        }
    }
}

// ---------------- Aggregation: z[n] = elu( sum_j alpha_j h[src_j] + b ) ------
// half-wave (32 lanes) per node, 8 nodes/block. Softmax without max-subtraction
// (scores bounded ~|10| << 88, shift-invariant). Score pass stores pre-scaled
// BYTE offsets (s*128) so the gather loop is one 32-bit add + saddr load.

__global__ __launch_bounds__(256) void k_agg(const int* __restrict__ rowptr, const int* __restrict__ csr,
                                             const float* __restrict__ ss, const float* __restrict__ sd,
                                             const unsigned int* __restrict__ hb, const float* __restrict__ bias,
                                             float* __restrict__ z, int N) {
    __shared__ float2 ps[8 * CAP];
    const int tid = threadIdx.x;
    const int hw  = tid >> 5;          // half-wave 0..7 (node slot)
    const int p   = tid & 31;
    const int n   = blockIdx.x * 8 + hw;
    const bool valid = n < N;
    float2* myps = ps + hw * CAP;
    const char* hbb = (const char*)hb;
    const int p4 = p * 4;

    int ro = 0, deg = 0;
    float sdn = 0.f;
    if (valid) {
        ro  = rowptr[n];
        deg = rowptr[n + 1] - ro;
        sdn = sd[n];
    }

    if (deg <= CAP) {
        float sum = 0.f;
        for (int j = p; j < deg; j += 32) {
            int s = csr[ro + j];
            float e = ss[s] + sdn;
            e = fmaxf(e, NEG_SLOPE * e);
            float pe = __expf(e);
            myps[j] = make_float2(pe, __int_as_float((s << 7) + p4 - p4));  // byte offset s*128
            sum += pe;
        }
        sum = hred_sum(sum);
        float inv = 1.f / (sum + 1e-16f);

        float ax = 0.f, ay = 0.f, bx = 0.f, by = 0.f, cx = 0.f, cy = 0.f, dx = 0.f, dy = 0.f;
        int j = 0;
        for (; j + 3 < deg; j += 4) {
            float2 e0 = myps[j], e1 = myps[j + 1], e2 = myps[j + 2], e3 = myps[j + 3];
            unsigned int u0 = *(const unsigned int*)(hbb + (__float_as_int(e0.y) + p4));
            unsigned int u1 = *(const unsigned int*)(hbb + (__float_as_int(e1.y) + p4));
            unsigned int u2 = *(const unsigned int*)(hbb + (__float_as_int(e2.y) + p4));
            unsigned int u3 = *(const unsigned int*)(hbb + (__float_as_int(e3.y) + p4));
            ax = fmaf(bflo(u0), e0.x, ax); ay = fmaf(bfhi(u0), e0.x, ay);
            bx = fmaf(bflo(u1), e1.x, bx); by = fmaf(bfhi(u1), e1.x, by);
            cx = fmaf(bflo(u2), e2.x, cx); cy = fmaf(bfhi(u2), e2.x, cy);
            dx = fmaf(bflo(u3), e3.x, dx); dy = fmaf(bfhi(u3), e3.x, dy);
        }
        for (; j < deg; ++j) {
            float2 e0 = myps[j];
            unsigned int u0 = *(const unsigned int*)(hbb + (__float_as_int(e0.y) + p4));
            ax = fmaf(bflo(u0), e0.x, ax); ay = fmaf(bfhi(u0), e0.x, ay);
        }
        float fx = (ax + bx) + (cx + dx);
        float fy = (ay + by) + (cy + dy);
        if (valid) {
            float2 ob = *(const float2*)&bias[p * 2];
            float ox = fmaf(fx, inv, ob.x);
            float oy = fmaf(fy, inv, ob.y);
            ox = (ox > 0.f) ? ox : __expf(ox) - 1.f;
            oy = (oy > 0.f) ? oy : __expf(oy) - 1.f;
            *(float2*)&z[(size_t)n * 64 + p * 2] = make_float2(ox, oy);
        }
    } else {
        float sum = 0.f;
        for (int j = p; j < deg; j += 32) {
            int s = csr[ro + j];
            float e = ss[s] + sdn;
            e = fmaxf(e, NEG_SLOPE * e);
            sum += __expf(e);
        }
        sum = hred_sum(sum);
        float inv = 1.f / (sum + 1e-16f);
        float fx = 0.f, fy = 0.f;
        for (int j = 0; j < deg; ++j) {
            int s = csr[ro + j];
            float e = ss[s] + sdn;
            e = fmaxf(e, NEG_SLOPE * e);
            float pe = __expf(e);
            unsigned int u = *(const unsigned int*)(hbb + ((s << 7) + p4));
            fx = fmaf(bflo(u), pe, fx); fy = fmaf(bfhi(u), pe, fy);
        }
        float2 ob = *(const float2*)&bias[p * 2];
        float ox = fmaf(fx, inv, ob.x);
        float oy = fmaf(fy, inv, ob.y);
        ox = (ox > 0.f) ? ox : __expf(ox) - 1.f;
        oy = (oy > 0.f) ? oy : __expf(oy) - 1.f;
        *(float2*)&z[(size_t)n * 64 + p * 2] = make_float2(ox, oy);
    }
}

// ---------------- launch ----------------

extern "C" void kernel_launch(void* const* d_in, const int* in_sizes, int n_in,
                              void* d_out, int out_size, void* d_ws, size_t ws_size,
                              hipStream_t stream) {
    const float* x   = (const float*)d_in[0];
    const int*   ei  = (const int*)d_in[1];
    const float* W0  = (const float*)d_in[2];
    const float* as0 = (const float*)d_in[3];
    const float* ad0 = (const float*)d_in[4];
    const float* b0  = (const float*)d_in[5];
    const float* W1  = (const float*)d_in[6];
    const float* as1 = (const float*)d_in[7];
    const float* ad1 = (const float*)d_in[8];
    const float* b1  = (const float*)d_in[9];
    const float* Wl  = (const float*)d_in[10];
    const float* bl  = (const float*)d_in[11];
    float* out = (float*)d_out;

    int N = in_sizes[0] / 128;
    int E = in_sizes[1] / 2;
    const int* srcp = ei;
    const int* dstp = ei + E;
    int nbuck = (N + BSZ - 1) >> BSH;

    char* wp = (char*)d_ws;
    auto alloc = [&](size_t bytes) { void* p = (void*)wp; wp += (bytes + 255) & ~(size_t)255; return p; };
    unsigned int* hb = (unsigned int*)alloc((size_t)N * 32 * 4);   // bf16-packed h
    float* z       = (float*)alloc((size_t)N * 64 * 4);
    float* ssb     = (float*)alloc((size_t)N * 4);
    float* sdb     = (float*)alloc((size_t)N * 4);
    int*   rowptr  = (int*)alloc((size_t)(N + 1) * 4);
    int*   csr     = (int*)alloc((size_t)(E + N) * 4);
    int*   ebuf    = (int*)alloc((size_t)E * 4);
    int*   bcount  = (int*)alloc(256 * PADS * 4);
    int*   eoff    = (int*)alloc(256 * 4);
    int*   boff    = (int*)alloc(256 * 4);
    int*   bcursor = (int*)alloc(256 * PADS * 4);

    // CSR build
    k_zero<<<(256 * PADS + 255) / 256, 256, 0, stream>>>(bcount, 256 * PADS);
    k_hist<<<256, 256, 0, stream>>>(dstp, bcount, E);
    k_bscan<<<1, 256, 0, stream>>>(bcount, eoff, boff, bcursor, rowptr, nbuck, N, E);
    k_scatter<<<(E + CHUNK - 1) / CHUNK, 256, 0, stream>>>(srcp, dstp, bcursor, ebuf, E);
    k_build<<<nbuck, 512, 0, stream>>>(eoff, boff, bcount, ebuf, rowptr, csr, N);

    int gb = (N + 63) / 64;
    // layer 0
    k_gemm<128, 64, true, true><<<gb, 256, 0, stream>>>(x, W0, as0, ad0, nullptr, hb, ssb, sdb, N);
    k_agg<<<(N + 7) / 8, 256, 0, stream>>>(rowptr, csr, ssb, sdb, hb, b0, z, N);
    // layer 1
    k_gemm<64, 64, true, true><<<gb, 256, 0, stream>>>(z, W1, as1, ad1, nullptr, hb, ssb, sdb, N);
    k_agg<<<(N + 7) / 8, 256, 0, stream>>>(rowptr, csr, ssb, sdb, hb, b1, z, N);
    // classifier
    k_gemm<64, 40, false, false><<<gb, 256, 0, stream>>>(z, Wl, nullptr, nullptr, bl, out, nullptr, nullptr, N);
}

// Round 9
// 271.459 us; speedup vs baseline: 1.0365x; 1.0365x over previous
//
#include <hip/hip_runtime.h>
#include <math.h>

#define NEG_SLOPE 0.2f
#define CAP 256     // max degree on the agg fast path
#define BSH 9       // node-bucket shift: 512 nodes/bucket
#define BSZ 512
#define CHUNK 2048  // edges per k_scatter block (8 per thread)
#define PADS 16     // counter padding (ints) -> one counter per 64B line

typedef __attribute__((ext_vector_type(8))) short short8;   // 8 bf16 (4 VGPRs)
typedef __attribute__((ext_vector_type(4))) float f32x4;    // MFMA C/D

__device__ __forceinline__ float hred_sum(float v) {   // 32-wide (half-wave) reduce
#pragma unroll
    for (int o = 16; o >= 1; o >>= 1) v += __shfl_xor(v, o, 64);
    return v;
}
// fp32 -> bf16 (RNE), and bf16(lo/hi of uint) -> fp32
__device__ __forceinline__ unsigned int f2bf(float f) {
    unsigned int u = __float_as_uint(f);
    return (u + 0x7fffu + ((u >> 16) & 1u)) >> 16;
}
__device__ __forceinline__ float bflo(unsigned int u) { return __uint_as_float(u << 16); }
__device__ __forceinline__ float bfhi(unsigned int u) { return __uint_as_float(u & 0xffff0000u); }

// ---------------- CSR build: bucketed counting sort ----------------

__global__ __launch_bounds__(256) void k_zero(int* p, int n) {
    int i = blockIdx.x * 256 + threadIdx.x;
    if (i < n) p[i] = 0;
}

__global__ __launch_bounds__(256) void k_hist(const int* __restrict__ dst, int* __restrict__ bcount, int E) {
    __shared__ int lh[256];
    lh[threadIdx.x] = 0;
    __syncthreads();
    int gid = blockIdx.x * 256 + threadIdx.x;
    int nth = gridDim.x * 256;
    int E4 = E >> 2;
    for (int i = gid; i < E4; i += nth) {
        int4 d = ((const int4*)dst)[i];
        atomicAdd(&lh[d.x >> BSH], 1);
        atomicAdd(&lh[d.y >> BSH], 1);
        atomicAdd(&lh[d.z >> BSH], 1);
        atomicAdd(&lh[d.w >> BSH], 1);
    }
    for (int i = (E4 << 2) + gid; i < E; i += nth)
        atomicAdd(&lh[dst[i] >> BSH], 1);
    __syncthreads();
    int c = lh[threadIdx.x];
    if (c) atomicAdd(&bcount[threadIdx.x * PADS], c);
}

__global__ __launch_bounds__(256) void k_bscan(const int* __restrict__ bcount,
                                               int* __restrict__ eoff, int* __restrict__ boff,
                                               int* __restrict__ bcursor, int* __restrict__ rowptr,
                                               int nbuck, int N, int E) {
    __shared__ int s1[256], s2[256];
    int t = threadIdx.x;
    int bc = (t < nbuck) ? bcount[t * PADS] : 0;
    int cn = 0;
    if (t < nbuck) { cn = N - (t << BSH); if (cn > BSZ) cn = BSZ; if (cn < 0) cn = 0; }
    int tot = bc + cn;
    s1[t] = bc; s2[t] = tot;
    __syncthreads();
#pragma unroll
    for (int off = 1; off < 256; off <<= 1) {
        int u1 = (t >= off) ? s1[t - off] : 0;
        int u2 = (t >= off) ? s2[t - off] : 0;
        __syncthreads();
        s1[t] += u1; s2[t] += u2;
        __syncthreads();
    }
    if (t < nbuck) {
        int e = s1[t] - bc, b = s2[t] - tot;
        eoff[t] = e; boff[t] = b; bcursor[t * PADS] = e;
    }
    if (t == 0) rowptr[N] = E + N;
}

// all 8 edges loaded into registers up front (16 loads in flight), then
// LDS hist -> burst reservation -> LDS-cursor scatter.
__global__ __launch_bounds__(256) void k_scatter(const int* __restrict__ src, const int* __restrict__ dst,
                                                 int* __restrict__ bcursor, int* __restrict__ ebuf, int E) {
    __shared__ int lh[256], lb[256];
    const int tid = threadIdx.x;
    int base = blockIdx.x * CHUNK;
    int sv[8], dv[8];
    bool ok[8];
#pragma unroll
    for (int u = 0; u < 8; ++u) {
        int i = base + u * 256 + tid;
        ok[u] = i < E;
        int ii = ok[u] ? i : E - 1;
        dv[u] = dst[ii];
        sv[u] = src[ii];
    }
    lh[tid] = 0;
    __syncthreads();
#pragma unroll
    for (int u = 0; u < 8; ++u)
        if (ok[u]) atomicAdd(&lh[dv[u] >> BSH], 1);
    __syncthreads();
    int c = lh[tid];
    lb[tid] = c ? atomicAdd(&bcursor[tid * PADS], c) : 0;
    lh[tid] = 0;
    __syncthreads();
#pragma unroll
    for (int u = 0; u < 8; ++u) {
        if (ok[u]) {
            int d = dv[u], b = d >> BSH;
            int p = atomicAdd(&lh[b], 1);
            ebuf[lb[b] + p] = (sv[u] << BSH) | (d & (BSZ - 1));
        }
    }
}

__global__ __launch_bounds__(512) void k_build(const int* __restrict__ eoff, const int* __restrict__ boff,
                                               const int* __restrict__ bcount, const int* __restrict__ ebuf,
                                               int* __restrict__ rowptr, int* __restrict__ csr, int N) {
    __shared__ int sdeg[BSZ], sscan[BSZ];
    int b = blockIdx.x, t = threadIdx.x;
    int nlo = b << BSH;
    int cn = N - nlo; if (cn > BSZ) cn = BSZ;
    int e0 = eoff[b], ec = bcount[b * PADS], cb = boff[b];
    sdeg[t] = (t < cn) ? 1 : 0;
    __syncthreads();
    {
        int i = t;
        for (; i + 1536 < ec; i += 2048) {
            int r0 = ebuf[e0 + i], r1 = ebuf[e0 + i + 512];
            int r2 = ebuf[e0 + i + 1024], r3 = ebuf[e0 + i + 1536];
            atomicAdd(&sdeg[r0 & (BSZ - 1)], 1);
            atomicAdd(&sdeg[r1 & (BSZ - 1)], 1);
            atomicAdd(&sdeg[r2 & (BSZ - 1)], 1);
            atomicAdd(&sdeg[r3 & (BSZ - 1)], 1);
        }
        for (; i < ec; i += 512)
            atomicAdd(&sdeg[ebuf[e0 + i] & (BSZ - 1)], 1);
    }
    __syncthreads();
    int v = sdeg[t];
    sscan[t] = v;
    __syncthreads();
#pragma unroll
    for (int off = 1; off < BSZ; off <<= 1) {
        int u = (t >= off) ? sscan[t - off] : 0;
        __syncthreads();
        sscan[t] += u;
        __syncthreads();
    }
    int excl = sscan[t] - v;
    if (t < cn) {
        rowptr[nlo + t] = cb + excl;
        csr[cb + excl] = nlo + t;
        sdeg[t] = excl + 1;
    }
    __syncthreads();
    {
        int i = t;
        for (; i + 1536 < ec; i += 2048) {
            int r0 = ebuf[e0 + i], r1 = ebuf[e0 + i + 512];
            int r2 = ebuf[e0 + i + 1024], r3 = ebuf[e0 + i + 1536];
            int p0 = atomicAdd(&sdeg[r0 & (BSZ - 1)], 1);
            int p1 = atomicAdd(&sdeg[r1 & (BSZ - 1)], 1);
            int p2 = atomicAdd(&sdeg[r2 & (BSZ - 1)], 1);
            int p3 = atomicAdd(&sdeg[r3 & (BSZ - 1)], 1);
            csr[cb + p0] = r0 >> BSH;
            csr[cb + p1] = r1 >> BSH;
            csr[cb + p2] = r2 >> BSH;
            csr[cb + p3] = r3 >> BSH;
        }
        for (; i < ec; i += 512) {
            int rec = ebuf[e0 + i];
            int p = atomicAdd(&sdeg[rec & (BSZ - 1)], 1);
            csr[cb + p] = rec >> BSH;
        }
    }
}

// ---------------- GEMM via bf16 MFMA, split-precision A ----------------------
// H = X @ W (+bias). Block = 256 = 4 waves; each wave: 16 rows x OUTW cols.
// A = xh + xl (two bf16 terms, ~fp32 accuracy); W plain bf16 (error ~6e-4).
// W pre-packed in LDS as B-fragments (one barrier total). A-frags loaded
// directly from global. MFMA 16x16x32:
//   A[m=lane&15][k=(lane>>4)*8+j], B[k][n=lane&15], C/D row=(lane>>4)*4+i.

template <int K, int OUTW, bool SS, bool HB>
__global__ __launch_bounds__(256) void k_gemm(const float* __restrict__ X,
                                              const float* __restrict__ W,
                                              const float* __restrict__ a_s,
                                              const float* __restrict__ a_d,
                                              const float* __restrict__ bias,
                                              void* __restrict__ Hout,
                                              float* __restrict__ ss,
                                              float* __restrict__ sd, int N) {
    constexpr int NKC = K / 32;               // k32 chunks
    constexpr int NC  = (OUTW + 15) / 16;     // 16-col tiles
    __shared__ __align__(16) short wfrag[NKC * NC * 64 * 8];
    __shared__ __align__(16) unsigned int hs[HB ? 4 : 1][16 * 32];  // per-wave epilogue

    const int tid  = threadIdx.x;
    const int lane = tid & 63;
    const int w    = tid >> 6;
    const int m    = lane & 15;     // A row / B col / C col
    const int q8   = lane >> 4;     // k-octet / C row-quad
    const int rowbase = blockIdx.x * 64 + w * 16;

    // stage W as pre-packed B-fragments (once)
    for (int f = tid; f < NKC * NC * 64; f += 256) {
        int flane = f & 63;
        int fc    = (f >> 6) % NC;
        int fkc   = (f >> 6) / NC;
        int col   = fc * 16 + (flane & 15);
        int k0    = fkc * 32 + (flane >> 4) * 8;
        short8 b;
#pragma unroll
        for (int j = 0; j < 8; ++j) {
            float v = (col < OUTW) ? W[(k0 + j) * OUTW + col] : 0.f;
            b[j] = (short)f2bf(v);
        }
        *(short8*)&wfrag[f * 8] = b;
    }
    __syncthreads();

    int grow = rowbase + m; if (grow >= N) grow = N - 1;
    const float* xrow = X + (size_t)grow * K + q8 * 8;

    f32x4 acc[NC];
#pragma unroll
    for (int c = 0; c < NC; ++c) acc[c] = (f32x4)0.f;

#pragma unroll
    for (int kc = 0; kc < NKC; ++kc) {
        float4 v0 = *(const float4*)(xrow + kc * 32);
        float4 v1 = *(const float4*)(xrow + kc * 32 + 4);
        float vv[8] = {v0.x, v0.y, v0.z, v0.w, v1.x, v1.y, v1.z, v1.w};
        short8 ah, al;
#pragma unroll
        for (int j = 0; j < 8; ++j) {
            unsigned int hb16 = f2bf(vv[j]);
            ah[j] = (short)hb16;
            al[j] = (short)f2bf(vv[j] - __uint_as_float(hb16 << 16));
        }
#pragma unroll
        for (int c = 0; c < NC; ++c) {
            short8 b = *(short8*)&wfrag[((kc * NC + c) * 64 + lane) * 8];
            acc[c] = __builtin_amdgcn_mfma_f32_16x16x32_bf16(ah, b, acc[c], 0, 0, 0);
            acc[c] = __builtin_amdgcn_mfma_f32_16x16x32_bf16(al, b, acc[c], 0, 0, 0);
        }
    }

    if (SS) {
        float asv[NC], adv[NC];
#pragma unroll
        for (int c = 0; c < NC; ++c) { asv[c] = a_s[c * 16 + m]; adv[c] = a_d[c * 16 + m]; }
#pragma unroll
        for (int i = 0; i < 4; ++i) {
            float s = 0.f, d = 0.f;
#pragma unroll
            for (int c = 0; c < NC; ++c) {
                s = fmaf(acc[c][i], asv[c], s);
                d = fmaf(acc[c][i], adv[c], d);
            }
#pragma unroll
            for (int o = 1; o <= 8; o <<= 1) {   // reduce the 16 col-lanes of this q8 group
                s += __shfl_xor(s, o, 64);
                d += __shfl_xor(d, o, 64);
            }
            int r = rowbase + q8 * 4 + i;
            if (m == 0 && r < N) { ss[r] = s; sd[r] = d; }
        }
    }

    if (HB) {
        // per-wave LDS transpose to bf16-packed rows (same-wave, no barrier needed)
        unsigned short* hsw = (unsigned short*)&hs[w][0];   // [16 rows][64 cols] bf16
#pragma unroll
        for (int c = 0; c < NC; ++c)
#pragma unroll
            for (int i = 0; i < 4; ++i)
                hsw[(q8 * 4 + i) * 64 + c * 16 + m] = (unsigned short)f2bf(acc[c][i]);
        unsigned int* hu = &hs[w][0];
        int row = lane >> 2, u0 = (lane & 3) * 8;
        uint4 va = *(uint4*)&hu[row * 32 + u0];
        uint4 vb = *(uint4*)&hu[row * 32 + u0 + 4];
        int r = rowbase + row;
        if (r < N) {
            unsigned int* hbp = (unsigned int*)Hout;
            *(uint4*)&hbp[(size_t)r * 32 + u0]     = va;
            *(uint4*)&hbp[(size_t)r * 32 + u0 + 4] = vb;
        }
    } else {
        float bv[NC];
#pragma unroll
        for (int c = 0; c < NC; ++c) {
            int col = c * 16 + m;
            bv[c] = (col < OUTW) ? bias[col] : 0.f;
        }
        float* O = (float*)Hout;
#pragma unroll
        for (int i = 0; i < 4; ++i) {
            int r = rowbase + q8 * 4 + i;
            if (r < N) {
#pragma unroll
                for (int c = 0; c < NC; ++c) {
                    int col = c * 16 + m;
                    if (col < OUTW) O[(size_t)r * OUTW + col] = acc[c][i] + bv[c];
                }
            }
        }
    }
}

// ---------------- Aggregation: z[n] = elu( sum_j alpha_j h[src_j] + b ) ------
// half-wave (32 lanes) per node, 8 nodes/block. Softmax without max-subtraction.
// Gather: 8 edges in flight (8 ds_read_b64 + 8 global loads issued before use).

__global__ __launch_bounds__(256) void k_agg(const int* __restrict__ rowptr, const int* __restrict__ csr,
                                             const float* __restrict__ ss, const float* __restrict__ sd,
                                             const unsigned int* __restrict__ hb, const float* __restrict__ bias,
                                             float* __restrict__ z, int N) {
    __shared__ float2 ps[8 * CAP];
    const int tid = threadIdx.x;
    const int hw  = tid >> 5;          // half-wave 0..7 (node slot)
    const int p   = tid & 31;
    const int n   = blockIdx.x * 8 + hw;
    const bool valid = n < N;
    float2* myps = ps + hw * CAP;
    const char* hbb = (const char*)hb;
    const int p4 = p * 4;

    int ro = 0, deg = 0;
    float sdn = 0.f;
    if (valid) {
        ro  = rowptr[n];
        deg = rowptr[n + 1] - ro;
        sdn = sd[n];
    }

    if (deg <= CAP) {
        float sum = 0.f;
        for (int j = p; j < deg; j += 32) {
            int s = csr[ro + j];
            float e = ss[s] + sdn;
            e = fmaxf(e, NEG_SLOPE * e);
            float pe = __expf(e);
            myps[j] = make_float2(pe, __int_as_float(s << 7));   // byte offset s*128
            sum += pe;
        }
        sum = hred_sum(sum);
        float inv = 1.f / (sum + 1e-16f);

        float ax = 0.f, ay = 0.f, bx = 0.f, by = 0.f, cx = 0.f, cy = 0.f, dx = 0.f, dy = 0.f;
        int j = 0;
        for (; j + 7 < deg; j += 8) {
            float2 e0 = myps[j],     e1 = myps[j + 1], e2 = myps[j + 2], e3 = myps[j + 3];
            float2 e4 = myps[j + 4], e5 = myps[j + 5], e6 = myps[j + 6], e7 = myps[j + 7];
            unsigned int u0 = *(const unsigned int*)(hbb + (__float_as_int(e0.y) + p4));
            unsigned int u1 = *(const unsigned int*)(hbb + (__float_as_int(e1.y) + p4));
            unsigned int u2 = *(const unsigned int*)(hbb + (__float_as_int(e2.y) + p4));
            unsigned int u3 = *(const unsigned int*)(hbb + (__float_as_int(e3.y) + p4));
            unsigned int u4 = *(const unsigned int*)(hbb + (__float_as_int(e4.y) + p4));
            unsigned int u5 = *(const unsigned int*)(hbb + (__float_as_int(e5.y) + p4));
            unsigned int u6 = *(const unsigned int*)(hbb + (__float_as_int(e6.y) + p4));
            unsigned int u7 = *(const unsigned int*)(hbb + (__float_as_int(e7.y) + p4));
            ax = fmaf(bflo(u0), e0.x, ax); ay = fmaf(bfhi(u0), e0.x, ay);
            bx = fmaf(bflo(u1), e1.x, bx); by = fmaf(bfhi(u1), e1.x, by);
            cx = fmaf(bflo(u2), e2.x, cx); cy = fmaf(bfhi(u2), e2.x, cy);
            dx = fmaf(bflo(u3), e3.x, dx); dy = fmaf(bfhi(u3), e3.x, dy);
            ax = fmaf(bflo(u4), e4.x, ax); ay = fmaf(bfhi(u4), e4.x, ay);
            bx = fmaf(bflo(u5), e5.x, bx); by = fmaf(bfhi(u5), e5.x, by);
            cx = fmaf(bflo(u6), e6.x, cx); cy = fmaf(bfhi(u6), e6.x, cy);
            dx = fmaf(bflo(u7), e7.x, dx); dy = fmaf(bfhi(u7), e7.x, dy);
        }
        for (; j + 3 < deg; j += 4) {
            float2 e0 = myps[j], e1 = myps[j + 1], e2 = myps[j + 2], e3 = myps[j + 3];
            unsigned int u0 = *(const unsigned int*)(hbb + (__float_as_int(e0.y) + p4));
            unsigned int u1 = *(const unsigned int*)(hbb + (__float_as_int(e1.y) + p4));
            unsigned int u2 = *(const unsigned int*)(hbb + (__float_as_int(e2.y) + p4));
            unsigned int u3 = *(const unsigned int*)(hbb + (__float_as_int(e3.y) + p4));
            ax = fmaf(bflo(u0), e0.x, ax); ay = fmaf(bfhi(u0), e0.x, ay);
            bx = fmaf(bflo(u1), e1.x, bx); by = fmaf(bfhi(u1), e1.x, by);
            cx = fmaf(bflo(u2), e2.x, cx); cy = fmaf(bfhi(u2), e2.x, cy);
            dx = fmaf(bflo(u3), e3.x, dx); dy = fmaf(bfhi(u3), e3.x, dy);
        }
        for (; j < deg; ++j) {
            float2 e0 = myps[j];
            unsigned int u0 = *(const unsigned int*)(hbb + (__float_as_int(e0.y) + p4));
            ax = fmaf(bflo(u0), e0.x, ax); ay = fmaf(bfhi(u0), e0.x, ay);
        }
        float fx = (ax + bx) + (cx + dx);
        float fy = (ay + by) + (cy + dy);
        if (valid) {
            float2 ob = *(const float2*)&bias[p * 2];
            float ox = fmaf(fx, inv, ob.x);
            float oy = fmaf(fy, inv, ob.y);
            ox = (ox > 0.f) ? ox : __expf(ox) - 1.f;
            oy = (oy > 0.f) ? oy : __expf(oy) - 1.f;
            *(float2*)&z[(size_t)n * 64 + p * 2] = make_float2(ox, oy);
        }
    } else {
        float sum = 0.f;
        for (int j = p; j < deg; j += 32) {
            int s = csr[ro + j];
            float e = ss[s] + sdn;
            e = fmaxf(e, NEG_SLOPE * e);
            sum += __expf(e);
        }
        sum = hred_sum(sum);
        float inv = 1.f / (sum + 1e-16f);
        float fx = 0.f, fy = 0.f;
        for (int j = 0; j < deg; ++j) {
            int s = csr[ro + j];
            float e = ss[s] + sdn;
            e = fmaxf(e, NEG_SLOPE * e);
            float pe = __expf(e);
            unsigned int u = *(const unsigned int*)(hbb + ((s << 7) + p4));
            fx = fmaf(bflo(u), pe, fx); fy = fmaf(bfhi(u), pe, fy);
        }
        float2 ob = *(const float2*)&bias[p * 2];
        float ox = fmaf(fx, inv, ob.x);
        float oy = fmaf(fy, inv, ob.y);
        ox = (ox > 0.f) ? ox : __expf(ox) - 1.f;
        oy = (oy > 0.f) ? oy : __expf(oy) - 1.f;
        *(float2*)&z[(size_t)n * 64 + p * 2] = make_float2(ox, oy);
    }
}

// ---------------- launch ----------------

extern "C" void kernel_launch(void* const* d_in, const int* in_sizes, int n_in,
                              void* d_out, int out_size, void* d_ws, size_t ws_size,
                              hipStream_t stream) {
    const float* x   = (const float*)d_in[0];
    const int*   ei  = (const int*)d_in[1];
    const float* W0  = (const float*)d_in[2];
    const float* as0 = (const float*)d_in[3];
    const float* ad0 = (const float*)d_in[4];
    const float* b0  = (const float*)d_in[5];
    const float* W1  = (const float*)d_in[6];
    const float* as1 = (const float*)d_in[7];
    const float* ad1 = (const float*)d_in[8];
    const float* b1  = (const float*)d_in[9];
    const float* Wl  = (const float*)d_in[10];
    const float* bl  = (const float*)d_in[11];
    float* out = (float*)d_out;

    int N = in_sizes[0] / 128;
    int E = in_sizes[1] / 2;
    const int* srcp = ei;
    const int* dstp = ei + E;
    int nbuck = (N + BSZ - 1) >> BSH;

    char* wp = (char*)d_ws;
    auto alloc = [&](size_t bytes) { void* p = (void*)wp; wp += (bytes + 255) & ~(size_t)255; return p; };
    unsigned int* hb = (unsigned int*)alloc((size_t)N * 32 * 4);   // bf16-packed h
    float* z       = (float*)alloc((size_t)N * 64 * 4);
    float* ssb     = (float*)alloc((size_t)N * 4);
    float* sdb     = (float*)alloc((size_t)N * 4);
    int*   rowptr  = (int*)alloc((size_t)(N + 1) * 4);
    int*   csr     = (int*)alloc((size_t)(E + N) * 4);
    int*   ebuf    = (int*)alloc((size_t)E * 4);
    int*   bcount  = (int*)alloc(256 * PADS * 4);
    int*   eoff    = (int*)alloc(256 * 4);
    int*   boff    = (int*)alloc(256 * 4);
    int*   bcursor = (int*)alloc(256 * PADS * 4);

    // CSR build
    k_zero<<<(256 * PADS + 255) / 256, 256, 0, stream>>>(bcount, 256 * PADS);
    k_hist<<<256, 256, 0, stream>>>(dstp, bcount, E);
    k_bscan<<<1, 256, 0, stream>>>(bcount, eoff, boff, bcursor, rowptr, nbuck, N, E);
    k_scatter<<<(E + CHUNK - 1) / CHUNK, 256, 0, stream>>>(srcp, dstp, bcursor, ebuf, E);
    k_build<<<nbuck, 512, 0, stream>>>(eoff, boff, bcount, ebuf, rowptr, csr, N);

    int gb = (N + 63) / 64;
    // layer 0
    k_gemm<128, 64, true, true><<<gb, 256, 0, stream>>>(x, W0, as0, ad0, nullptr, hb, ssb, sdb, N);
    k_agg<<<(N + 7) / 8, 256, 0, stream>>>(rowptr, csr, ssb, sdb, hb, b0, z, N);
    // layer 1
    k_gemm<64, 64, true, true><<<gb, 256, 0, stream>>>(z, W1, as1, ad1, nullptr, hb, ssb, sdb, N);
    k_agg<<<(N + 7) / 8, 256, 0, stream>>>(rowptr, csr, ssb, sdb, hb, b1, z, N);
    // classifier
    k_gemm<64, 40, false, false><<<gb, 256, 0, stream>>>(z, Wl, nullptr, nullptr, bl, out, nullptr, nullptr, N);
}

// Round 10
// 266.553 us; speedup vs baseline: 1.0556x; 1.0184x over previous
//
#include <hip/hip_runtime.h>
#include <math.h>

#define NEG_SLOPE 0.2f
#define CAP 256     // max degree on the agg fast path
#define BSH 9       // node-bucket shift: 512 nodes/bucket
#define BSZ 512
#define CHUNK 2048  // edges per k_scatter block (8 per thread)
#define PADS 16     // counter padding (ints) -> one counter per 64B line
#define HGRID 256   // k_hist grid (fixed; bpart sized to it)

typedef __attribute__((ext_vector_type(8))) short short8;   // 8 bf16 (4 VGPRs)
typedef __attribute__((ext_vector_type(4))) float f32x4;    // MFMA C/D

__device__ __forceinline__ float hred_sum(float v) {   // 32-wide (half-wave) reduce
#pragma unroll
    for (int o = 16; o >= 1; o >>= 1) v += __shfl_xor(v, o, 64);
    return v;
}
// fp32 -> bf16 (RNE), and bf16(lo/hi of uint) -> fp32
__device__ __forceinline__ unsigned int f2bf(float f) {
    unsigned int u = __float_as_uint(f);
    return (u + 0x7fffu + ((u >> 16) & 1u)) >> 16;
}
__device__ __forceinline__ float bflo(unsigned int u) { return __uint_as_float(u << 16); }
__device__ __forceinline__ float bfhi(unsigned int u) { return __uint_as_float(u & 0xffff0000u); }

// ---------------- CSR build: bucketed counting sort ----------------

// per-block partial histograms: no global atomics, no pre-zero kernel
__global__ __launch_bounds__(256) void k_hist(const int* __restrict__ dst, int* __restrict__ bpart, int E) {
    __shared__ int lh[256];
    lh[threadIdx.x] = 0;
    __syncthreads();
    int gid = blockIdx.x * 256 + threadIdx.x;
    int nth = gridDim.x * 256;
    int E4 = E >> 2;
    for (int i = gid; i < E4; i += nth) {
        int4 d = ((const int4*)dst)[i];
        atomicAdd(&lh[d.x >> BSH], 1);
        atomicAdd(&lh[d.y >> BSH], 1);
        atomicAdd(&lh[d.z >> BSH], 1);
        atomicAdd(&lh[d.w >> BSH], 1);
    }
    for (int i = (E4 << 2) + gid; i < E; i += nth)
        atomicAdd(&lh[dst[i] >> BSH], 1);
    __syncthreads();
    bpart[blockIdx.x * 256 + threadIdx.x] = lh[threadIdx.x];
}

__global__ __launch_bounds__(256) void k_bscan(const int* __restrict__ bpart,
                                               int* __restrict__ eoff, int* __restrict__ boff,
                                               int* __restrict__ bcursor, int* __restrict__ ecnt,
                                               int* __restrict__ rowptr,
                                               int nbuck, int N, int E) {
    __shared__ int s1[256], s2[256];
    int t = threadIdx.x;
    int bc = 0;
    for (int b = 0; b < HGRID; b += 4) {
        bc += bpart[(b + 0) * 256 + t];
        bc += bpart[(b + 1) * 256 + t];
        bc += bpart[(b + 2) * 256 + t];
        bc += bpart[(b + 3) * 256 + t];
    }
    if (t >= nbuck) bc = 0;
    int cn = 0;
    if (t < nbuck) { cn = N - (t << BSH); if (cn > BSZ) cn = BSZ; if (cn < 0) cn = 0; }
    int tot = bc + cn;
    s1[t] = bc; s2[t] = tot;
    __syncthreads();
#pragma unroll
    for (int off = 1; off < 256; off <<= 1) {
        int u1 = (t >= off) ? s1[t - off] : 0;
        int u2 = (t >= off) ? s2[t - off] : 0;
        __syncthreads();
        s1[t] += u1; s2[t] += u2;
        __syncthreads();
    }
    if (t < nbuck) {
        int e = s1[t] - bc, b = s2[t] - tot;
        eoff[t] = e; boff[t] = b; ecnt[t] = bc; bcursor[t * PADS] = e;
    }
    if (t == 0) rowptr[N] = E + N;
}

// all 8 edges loaded into registers up front, then LDS hist -> burst
// reservation -> LDS-cursor scatter.
__global__ __launch_bounds__(256) void k_scatter(const int* __restrict__ src, const int* __restrict__ dst,
                                                 int* __restrict__ bcursor, int* __restrict__ ebuf, int E) {
    __shared__ int lh[256], lb[256];
    const int tid = threadIdx.x;
    int base = blockIdx.x * CHUNK;
    int sv[8], dv[8];
    bool ok[8];
#pragma unroll
    for (int u = 0; u < 8; ++u) {
        int i = base + u * 256 + tid;
        ok[u] = i < E;
        int ii = ok[u] ? i : E - 1;
        dv[u] = dst[ii];
        sv[u] = src[ii];
    }
    lh[tid] = 0;
    __syncthreads();
#pragma unroll
    for (int u = 0; u < 8; ++u)
        if (ok[u]) atomicAdd(&lh[dv[u] >> BSH], 1);
    __syncthreads();
    int c = lh[tid];
    lb[tid] = c ? atomicAdd(&bcursor[tid * PADS], c) : 0;
    lh[tid] = 0;
    __syncthreads();
#pragma unroll
    for (int u = 0; u < 8; ++u) {
        if (ok[u]) {
            int d = dv[u], b = d >> BSH;
            int p = atomicAdd(&lh[b], 1);
            ebuf[lb[b] + p] = (sv[u] << BSH) | (d & (BSZ - 1));
        }
    }
}

__global__ __launch_bounds__(512) void k_build(const int* __restrict__ eoff, const int* __restrict__ boff,
                                               const int* __restrict__ ecnt, const int* __restrict__ ebuf,
                                               int* __restrict__ rowptr, int* __restrict__ csr, int N) {
    __shared__ int sdeg[BSZ], sscan[BSZ];
    int b = blockIdx.x, t = threadIdx.x;
    int nlo = b << BSH;
    int cn = N - nlo; if (cn > BSZ) cn = BSZ;
    int e0 = eoff[b], ec = ecnt[b], cb = boff[b];
    sdeg[t] = (t < cn) ? 1 : 0;
    __syncthreads();
    {
        int i = t;
        for (; i + 1536 < ec; i += 2048) {
            int r0 = ebuf[e0 + i], r1 = ebuf[e0 + i + 512];
            int r2 = ebuf[e0 + i + 1024], r3 = ebuf[e0 + i + 1536];
            atomicAdd(&sdeg[r0 & (BSZ - 1)], 1);
            atomicAdd(&sdeg[r1 & (BSZ - 1)], 1);
            atomicAdd(&sdeg[r2 & (BSZ - 1)], 1);
            atomicAdd(&sdeg[r3 & (BSZ - 1)], 1);
        }
        for (; i < ec; i += 512)
            atomicAdd(&sdeg[ebuf[e0 + i] & (BSZ - 1)], 1);
    }
    __syncthreads();
    int v = sdeg[t];
    sscan[t] = v;
    __syncthreads();
#pragma unroll
    for (int off = 1; off < BSZ; off <<= 1) {
        int u = (t >= off) ? sscan[t - off] : 0;
        __syncthreads();
        sscan[t] += u;
        __syncthreads();
    }
    int excl = sscan[t] - v;
    if (t < cn) {
        rowptr[nlo + t] = cb + excl;
        csr[cb + excl] = nlo + t;
        sdeg[t] = excl + 1;
    }
    __syncthreads();
    {
        int i = t;
        for (; i + 1536 < ec; i += 2048) {
            int r0 = ebuf[e0 + i], r1 = ebuf[e0 + i + 512];
            int r2 = ebuf[e0 + i + 1024], r3 = ebuf[e0 + i + 1536];
            int p0 = atomicAdd(&sdeg[r0 & (BSZ - 1)], 1);
            int p1 = atomicAdd(&sdeg[r1 & (BSZ - 1)], 1);
            int p2 = atomicAdd(&sdeg[r2 & (BSZ - 1)], 1);
            int p3 = atomicAdd(&sdeg[r3 & (BSZ - 1)], 1);
            csr[cb + p0] = r0 >> BSH;
            csr[cb + p1] = r1 >> BSH;
            csr[cb + p2] = r2 >> BSH;
            csr[cb + p3] = r3 >> BSH;
        }
        for (; i < ec; i += 512) {
            int rec = ebuf[e0 + i];
            int p = atomicAdd(&sdeg[rec & (BSZ - 1)], 1);
            csr[cb + p] = rec >> BSH;
        }
    }
}

// ---------------- GEMM via bf16 MFMA ----------------------
// H = X @ W (+bias). Block = 256 = 4 waves; each wave: 16 rows x OUTW cols.
// XB=false: fp32 X, split-precision A (xh+xl, ~fp32 accuracy), 2 MFMA/tile.
// XB=true:  X is bf16-packed rows (32 uints), direct 16B A-frag load, 1 MFMA.
// W bf16 pre-packed in LDS as B-fragments (one barrier). MFMA 16x16x32:
//   A[m=lane&15][k=(lane>>4)*8+j], B[k][n=lane&15], C/D row=(lane>>4)*4+i.

template <int K, int OUTW, bool SS, bool HB, bool XB>
__global__ __launch_bounds__(256) void k_gemm(const void* __restrict__ X,
                                              const float* __restrict__ W,
                                              const float* __restrict__ a_s,
                                              const float* __restrict__ a_d,
                                              const float* __restrict__ bias,
                                              void* __restrict__ Hout,
                                              float* __restrict__ ss,
                                              float* __restrict__ sd, int N) {
    constexpr int NKC = K / 32;               // k32 chunks
    constexpr int NC  = (OUTW + 15) / 16;     // 16-col tiles
    __shared__ __align__(16) short wfrag[NKC * NC * 64 * 8];
    __shared__ __align__(16) unsigned int hs[HB ? 4 : 1][16 * 32];  // per-wave epilogue

    const int tid  = threadIdx.x;
    const int lane = tid & 63;
    const int w    = tid >> 6;
    const int m    = lane & 15;     // A row / B col / C col
    const int q8   = lane >> 4;     // k-octet / C row-quad
    const int rowbase = blockIdx.x * 64 + w * 16;

    // stage W as pre-packed B-fragments (once)
    for (int f = tid; f < NKC * NC * 64; f += 256) {
        int flane = f & 63;
        int fc    = (f >> 6) % NC;
        int fkc   = (f >> 6) / NC;
        int col   = fc * 16 + (flane & 15);
        int k0    = fkc * 32 + (flane >> 4) * 8;
        short8 b;
#pragma unroll
        for (int j = 0; j < 8; ++j) {
            float v = (col < OUTW) ? W[(k0 + j) * OUTW + col] : 0.f;
            b[j] = (short)f2bf(v);
        }
        *(short8*)&wfrag[f * 8] = b;
    }
    __syncthreads();

    int grow = rowbase + m; if (grow >= N) grow = N - 1;

    f32x4 acc[NC];
#pragma unroll
    for (int c = 0; c < NC; ++c) acc[c] = (f32x4)0.f;

    if (XB) {
        const unsigned short* xrow = (const unsigned short*)X + (size_t)grow * 64 + q8 * 8;
#pragma unroll
        for (int kc = 0; kc < NKC; ++kc) {
            short8 ah = *(const short8*)(xrow + kc * 32);
#pragma unroll
            for (int c = 0; c < NC; ++c) {
                short8 b = *(short8*)&wfrag[((kc * NC + c) * 64 + lane) * 8];
                acc[c] = __builtin_amdgcn_mfma_f32_16x16x32_bf16(ah, b, acc[c], 0, 0, 0);
            }
        }
    } else {
        const float* xrow = (const float*)X + (size_t)grow * K + q8 * 8;
#pragma unroll
        for (int kc = 0; kc < NKC; ++kc) {
            float4 v0 = *(const float4*)(xrow + kc * 32);
            float4 v1 = *(const float4*)(xrow + kc * 32 + 4);
            float vv[8] = {v0.x, v0.y, v0.z, v0.w, v1.x, v1.y, v1.z, v1.w};
            short8 ah, al;
#pragma unroll
            for (int j = 0; j < 8; ++j) {
                unsigned int hb16 = f2bf(vv[j]);
                ah[j] = (short)hb16;
                al[j] = (short)f2bf(vv[j] - __uint_as_float(hb16 << 16));
            }
#pragma unroll
            for (int c = 0; c < NC; ++c) {
                short8 b = *(short8*)&wfrag[((kc * NC + c) * 64 + lane) * 8];
                acc[c] = __builtin_amdgcn_mfma_f32_16x16x32_bf16(ah, b, acc[c], 0, 0, 0);
                acc[c] = __builtin_amdgcn_mfma_f32_16x16x32_bf16(al, b, acc[c], 0, 0, 0);
            }
        }
    }

    if (SS) {
        float asv[NC], adv[NC];
#pragma unroll
        for (int c = 0; c < NC; ++c) { asv[c] = a_s[c * 16 + m]; adv[c] = a_d[c * 16 + m]; }
#pragma unroll
        for (int i = 0; i < 4; ++i) {
            float s = 0.f, d = 0.f;
#pragma unroll
            for (int c = 0; c < NC; ++c) {
                s = fmaf(acc[c][i], asv[c], s);
                d = fmaf(acc[c][i], adv[c], d);
            }
#pragma unroll
            for (int o = 1; o <= 8; o <<= 1) {   // reduce the 16 col-lanes of this q8 group
                s += __shfl_xor(s, o, 64);
                d += __shfl_xor(d, o, 64);
            }
            int r = rowbase + q8 * 4 + i;
            if (m == 0 && r < N) { ss[r] = s; sd[r] = d; }
        }
    }

    if (HB) {
        // per-wave LDS transpose to bf16-packed rows (same-wave, no barrier needed)
        unsigned short* hsw = (unsigned short*)&hs[w][0];   // [16 rows][64 cols] bf16
#pragma unroll
        for (int c = 0; c < NC; ++c)
#pragma unroll
            for (int i = 0; i < 4; ++i)
                hsw[(q8 * 4 + i) * 64 + c * 16 + m] = (unsigned short)f2bf(acc[c][i]);
        unsigned int* hu = &hs[w][0];
        int row = lane >> 2, u0 = (lane & 3) * 8;
        uint4 va = *(uint4*)&hu[row * 32 + u0];
        uint4 vb = *(uint4*)&hu[row * 32 + u0 + 4];
        int r = rowbase + row;
        if (r < N) {
            unsigned int* hbp = (unsigned int*)Hout;
            *(uint4*)&hbp[(size_t)r * 32 + u0]     = va;
            *(uint4*)&hbp[(size_t)r * 32 + u0 + 4] = vb;
        }
    } else {
        float bv[NC];
#pragma unroll
        for (int c = 0; c < NC; ++c) {
            int col = c * 16 + m;
            bv[c] = (col < OUTW) ? bias[col] : 0.f;
        }
        float* O = (float*)Hout;
#pragma unroll
        for (int i = 0; i < 4; ++i) {
            int r = rowbase + q8 * 4 + i;
            if (r < N) {
#pragma unroll
                for (int c = 0; c < NC; ++c) {
                    int col = c * 16 + m;
                    if (col < OUTW) O[(size_t)r * OUTW + col] = acc[c][i] + bv[c];
                }
            }
        }
    }
}

// ---------------- Aggregation: z[n] = elu( sum_j alpha_j h[src_j] + b ) ------
// half-wave (32 lanes) per node, 8 nodes/block. Softmax without max-subtraction.
// SoA LDS (alpha / byte-offset) -> b128 LDS reads in the gather loop.
// Output z is bf16-packed (uint pair per lane), consumed by XB gemms.

__global__ __launch_bounds__(256) void k_agg(const int* __restrict__ rowptr, const int* __restrict__ csr,
                                             const float* __restrict__ ss, const float* __restrict__ sd,
                                             const unsigned int* __restrict__ hb, const float* __restrict__ bias,
                                             unsigned int* __restrict__ z, int N) {
    __shared__ __align__(16) float sal[8][CAP];
    __shared__ __align__(16) int   sof[8][CAP];
    const int tid = threadIdx.x;
    const int hw  = tid >> 5;          // half-wave 0..7 (node slot)
    const int p   = tid & 31;
    const int n   = blockIdx.x * 8 + hw;
    const bool valid = n < N;
    const char* hbb = (const char*)hb;
    const int p4 = p * 4;

    int ro = 0, deg = 0;
    float sdn = 0.f;
    if (valid) {
        ro  = rowptr[n];
        deg = rowptr[n + 1] - ro;
        sdn = sd[n];
    }

    if (deg <= CAP) {
        float sum = 0.f;
        for (int j = p; j < deg; j += 32) {
            int s = csr[ro + j];
            float e = ss[s] + sdn;
            e = fmaxf(e, NEG_SLOPE * e);
            float pe = __expf(e);
            sal[hw][j] = pe;
            sof[hw][j] = s << 7;       // byte offset s*128
            sum += pe;
        }
        sum = hred_sum(sum);
        float inv = 1.f / (sum + 1e-16f);

        float ax = 0.f, ay = 0.f, bx = 0.f, by = 0.f, cx = 0.f, cy = 0.f, dx = 0.f, dy = 0.f;
        int j = 0;
        for (; j + 7 < deg; j += 8) {
            float4 al0 = *(const float4*)&sal[hw][j];
            float4 al1 = *(const float4*)&sal[hw][j + 4];
            int4   of0 = *(const int4*)&sof[hw][j];
            int4   of1 = *(const int4*)&sof[hw][j + 4];
            unsigned int u0 = *(const unsigned int*)(hbb + (of0.x + p4));
            unsigned int u1 = *(const unsigned int*)(hbb + (of0.y + p4));
            unsigned int u2 = *(const unsigned int*)(hbb + (of0.z + p4));
            unsigned int u3 = *(const unsigned int*)(hbb + (of0.w + p4));
            unsigned int u4 = *(const unsigned int*)(hbb + (of1.x + p4));
            unsigned int u5 = *(const unsigned int*)(hbb + (of1.y + p4));
            unsigned int u6 = *(const unsigned int*)(hbb + (of1.z + p4));
            unsigned int u7 = *(const unsigned int*)(hbb + (of1.w + p4));
            ax = fmaf(bflo(u0), al0.x, ax); ay = fmaf(bfhi(u0), al0.x, ay);
            bx = fmaf(bflo(u1), al0.y, bx); by = fmaf(bfhi(u1), al0.y, by);
            cx = fmaf(bflo(u2), al0.z, cx); cy = fmaf(bfhi(u2), al0.z, cy);
            dx = fmaf(bflo(u3), al0.w, dx); dy = fmaf(bfhi(u3), al0.w, dy);
            ax = fmaf(bflo(u4), al1.x, ax); ay = fmaf(bfhi(u4), al1.x, ay);
            bx = fmaf(bflo(u5), al1.y, bx); by = fmaf(bfhi(u5), al1.y, by);
            cx = fmaf(bflo(u6), al1.z, cx); cy = fmaf(bfhi(u6), al1.z, cy);
            dx = fmaf(bflo(u7), al1.w, dx); dy = fmaf(bfhi(u7), al1.w, dy);
        }
        for (; j + 3 < deg; j += 4) {
            float4 al0 = *(const float4*)&sal[hw][j];
            int4   of0 = *(const int4*)&sof[hw][j];
            unsigned int u0 = *(const unsigned int*)(hbb + (of0.x + p4));
            unsigned int u1 = *(const unsigned int*)(hbb + (of0.y + p4));
            unsigned int u2 = *(const unsigned int*)(hbb + (of0.z + p4));
            unsigned int u3 = *(const unsigned int*)(hbb + (of0.w + p4));
            ax = fmaf(bflo(u0), al0.x, ax); ay = fmaf(bfhi(u0), al0.x, ay);
            bx = fmaf(bflo(u1), al0.y, bx); by = fmaf(bfhi(u1), al0.y, by);
            cx = fmaf(bflo(u2), al0.z, cx); cy = fmaf(bfhi(u2), al0.z, cy);
            dx = fmaf(bflo(u3), al0.w, dx); dy = fmaf(bfhi(u3), al0.w, dy);
        }
        for (; j < deg; ++j) {
            float a = sal[hw][j];
            unsigned int u0 = *(const unsigned int*)(hbb + (sof[hw][j] + p4));
            ax = fmaf(bflo(u0), a, ax); ay = fmaf(bfhi(u0), a, ay);
        }
        float fx = (ax + bx) + (cx + dx);
        float fy = (ay + by) + (cy + dy);
        if (valid) {
            float2 ob = *(const float2*)&bias[p * 2];
            float ox = fmaf(fx, inv, ob.x);
            float oy = fmaf(fy, inv, ob.y);
            ox = (ox > 0.f) ? ox : __expf(ox) - 1.f;
            oy = (oy > 0.f) ? oy : __expf(oy) - 1.f;
            z[(size_t)n * 32 + p] = (f2bf(oy) << 16) | f2bf(ox);
        }
    } else {
        float sum = 0.f;
        for (int j = p; j < deg; j += 32) {
            int s = csr[ro + j];
            float e = ss[s] + sdn;
            e = fmaxf(e, NEG_SLOPE * e);
            sum += __expf(e);
        }
        sum = hred_sum(sum);
        float inv = 1.f / (sum + 1e-16f);
        float fx = 0.f, fy = 0.f;
        for (int j = 0; j < deg; ++j) {
            int s = csr[ro + j];
            float e = ss[s] + sdn;
            e = fmaxf(e, NEG_SLOPE * e);
            float pe = __expf(e);
            unsigned int u = *(const unsigned int*)(hbb + ((s << 7) + p4));
            fx = fmaf(bflo(u), pe, fx); fy = fmaf(bfhi(u), pe, fy);
        }
        float2 ob = *(const float2*)&bias[p * 2];
        float ox = fmaf(fx, inv, ob.x);
        float oy = fmaf(fy, inv, ob.y);
        ox = (ox > 0.f) ? ox : __expf(ox) - 1.f;
        oy = (oy > 0.f) ? oy : __expf(oy) - 1.f;
        z[(size_t)n * 32 + p] = (f2bf(oy) << 16) | f2bf(ox);
    }
}

// ---------------- launch ----------------

extern "C" void kernel_launch(void* const* d_in, const int* in_sizes, int n_in,
                              void* d_out, int out_size, void* d_ws, size_t ws_size,
                              hipStream_t stream) {
    const float* x   = (const float*)d_in[0];
    const int*   ei  = (const int*)d_in[1];
    const float* W0  = (const float*)d_in[2];
    const float* as0 = (const float*)d_in[3];
    const float* ad0 = (const float*)d_in[4];
    const float* b0  = (const float*)d_in[5];
    const float* W1  = (const float*)d_in[6];
    const float* as1 = (const float*)d_in[7];
    const float* ad1 = (const float*)d_in[8];
    const float* b1  = (const float*)d_in[9];
    const float* Wl  = (const float*)d_in[10];
    const float* bl  = (const float*)d_in[11];
    float* out = (float*)d_out;

    int N = in_sizes[0] / 128;
    int E = in_sizes[1] / 2;
    const int* srcp = ei;
    const int* dstp = ei + E;
    int nbuck = (N + BSZ - 1) >> BSH;

    char* wp = (char*)d_ws;
    auto alloc = [&](size_t bytes) { void* p = (void*)wp; wp += (bytes + 255) & ~(size_t)255; return p; };
    unsigned int* hb = (unsigned int*)alloc((size_t)N * 32 * 4);   // bf16-packed h
    unsigned int* z  = (unsigned int*)alloc((size_t)N * 32 * 4);   // bf16-packed z
    float* ssb     = (float*)alloc((size_t)N * 4);
    float* sdb     = (float*)alloc((size_t)N * 4);
    int*   rowptr  = (int*)alloc((size_t)(N + 1) * 4);
    int*   csr     = (int*)alloc((size_t)(E + N) * 4);
    int*   ebuf    = (int*)alloc((size_t)E * 4);
    int*   bpart   = (int*)alloc((size_t)HGRID * 256 * 4);
    int*   eoff    = (int*)alloc(256 * 4);
    int*   boff    = (int*)alloc(256 * 4);
    int*   ecnt    = (int*)alloc(256 * 4);
    int*   bcursor = (int*)alloc(256 * PADS * 4);

    // CSR build
    k_hist<<<HGRID, 256, 0, stream>>>(dstp, bpart, E);
    k_bscan<<<1, 256, 0, stream>>>(bpart, eoff, boff, bcursor, ecnt, rowptr, nbuck, N, E);
    k_scatter<<<(E + CHUNK - 1) / CHUNK, 256, 0, stream>>>(srcp, dstp, bcursor, ebuf, E);
    k_build<<<nbuck, 512, 0, stream>>>(eoff, boff, ecnt, ebuf, rowptr, csr, N);

    int gb = (N + 63) / 64;
    // layer 0 (fp32 x input, split-A)
    k_gemm<128, 64, true, true, false><<<gb, 256, 0, stream>>>(x, W0, as0, ad0, nullptr, hb, ssb, sdb, N);
    k_agg<<<(N + 7) / 8, 256, 0, stream>>>(rowptr, csr, ssb, sdb, hb, b0, z, N);
    // layer 1 (bf16 z input)
    k_gemm<64, 64, true, true, true><<<gb, 256, 0, stream>>>(z, W1, as1, ad1, nullptr, hb, ssb, sdb, N);
    k_agg<<<(N + 7) / 8, 256, 0, stream>>>(rowptr, csr, ssb, sdb, hb, b1, z, N);
    // classifier (bf16 z input, fp32 out)
    k_gemm<64, 40, false, false, true><<<gb, 256, 0, stream>>>(z, Wl, nullptr, nullptr, bl, out, nullptr, nullptr, N);
}